// Round 4
// baseline (220.508 us; speedup 1.0000x reference)
//
#include <hip/hip_runtime.h>

typedef _Float16 f16;
typedef _Float16 half8 __attribute__((ext_vector_type(8)));
typedef _Float16 half4v __attribute__((ext_vector_type(4)));
typedef float floatx4 __attribute__((ext_vector_type(4)));

#define B_ 64
#define T_ 256
#define C_ 384
#define H_ 6
#define D_ 64
#define NROWS (B_*T_)

typedef __attribute__((address_space(3))) void lds_void_t;
typedef const __attribute__((address_space(1))) void gvoid_t;

__device__ __forceinline__ void g2lds16(const void* g, void* l) {
  __builtin_amdgcn_global_load_lds((gvoid_t*)g, (lds_void_t*)l, 16, 0, 0);
}

// ---------------- fused prep (weight repack fp32->f16 B^T) + LN1 ----------------
__global__ __launch_bounds__(256) void prep_ln_kernel(
    const float* __restrict__ Wq, const float* __restrict__ Wk, const float* __restrict__ Wv,
    const float* __restrict__ bq, const float* __restrict__ bk, const float* __restrict__ bv,
    const float* __restrict__ Wp, const float* __restrict__ W1, const float* __restrict__ W2,
    f16* __restrict__ Wqkv_t, f16* __restrict__ Wp_t, f16* __restrict__ W1_t, f16* __restrict__ W2_t,
    float* __restrict__ bqkv,
    const float* __restrict__ x, const float* __restrict__ gamma, const float* __restrict__ beta,
    f16* __restrict__ hout)
{
  const int bid = blockIdx.x;
  const int tid = threadIdx.x;
  if (bid >= 217) {
    int row = (bid - 217) * 4 + (tid >> 6);
    int lane = tid & 63;
    const float* xr = x + (size_t)row * 384;
    float v[6]; float s = 0.f;
#pragma unroll
    for (int j = 0; j < 6; j++) { v[j] = xr[lane + 64*j]; s += v[j]; }
#pragma unroll
    for (int m = 1; m < 64; m <<= 1) s += __shfl_xor(s, m);
    float mu = s * (1.f/384.f);
    float var = 0.f;
#pragma unroll
    for (int j = 0; j < 6; j++) { float d = v[j]-mu; var += d*d; }
#pragma unroll
    for (int m = 1; m < 64; m <<= 1) var += __shfl_xor(var, m);
    float rs = rsqrtf(var * (1.f/384.f) + 1e-5f);
    f16* orow = hout + (size_t)row*384;
#pragma unroll
    for (int j = 0; j < 6; j++) {
      int col = lane + 64*j;
      orow[col] = (f16)((v[j]-mu)*rs*gamma[col] + beta[col]);
    }
    return;
  }
  if (bid == 216) {
    for (int i = tid; i < 1152; i += 256) {
      float v;
      if (i < 384)      v = bq[i];
      else if (i < 768) v = bk[i - 384];
      else              v = bv[i - 768];
      bqkv[i] = v;
    }
    return;
  }
  __shared__ __align__(16) float tile[64*68];
  const float* src; int srcStride; f16* dst;
  if (bid < 108) {
    int mat = bid / 36, rem = bid - mat*36;
    int h = rem / 6, kt = rem - h*6;
    const float* W = (mat == 0) ? Wq : (mat == 1) ? Wk : Wv;
    src = W + (size_t)(h*384 + kt*64)*64;
    srcStride = 64;
    dst = Wqkv_t + (size_t)(mat*384 + h*64)*384 + kt*64;
  } else {
    int b2 = bid - 108;
    int mat = b2 / 36, rem = b2 - mat*36;
    int kt = rem / 6, ct = rem - kt*6;
    const float* W = (mat == 0) ? Wp : (mat == 1) ? W1 : W2;
    src = W + (size_t)(kt*64)*384 + ct*64;
    srcStride = 384;
    f16* O = (mat == 0) ? Wp_t : (mat == 1) ? W1_t : W2_t;
    dst = O + (size_t)(ct*64)*384 + kt*64;
  }
#pragma unroll
  for (int i = 0; i < 4; i++) {
    int idx = i*256 + tid;
    int r = idx >> 4, c4 = idx & 15;
    float4 v = *(const float4*)(src + (size_t)r*srcStride + c4*4);
    *(float4*)(&tile[r*68 + c4*4]) = v;
  }
  __syncthreads();
#pragma unroll
  for (int i = 0; i < 4; i++) {
    int idx = i*256 + tid;
    int d = idx >> 4, k4 = idx & 15;
    half4v o;
#pragma unroll
    for (int j = 0; j < 4; j++) o[j] = (f16)tile[(k4*4 + j)*68 + d];
    *(half4v*)(dst + (size_t)d*384 + k4*4) = o;
  }
}

// ---------------- GEMM (QKV): C[M,1152] = A[M,384] @ Bt^T + bias, BK=64, f16 out ----------------
__global__ __launch_bounds__(256) void gemm_qkv_kernel(
    const f16* __restrict__ A, const f16* __restrict__ Bt,
    const float* __restrict__ bias, f16* __restrict__ outp, int ldo)
{
  __shared__ __align__(16) f16 As[2][128*32];
  __shared__ __align__(16) f16 Bs[2][128*32];
  const int tid = threadIdx.x;
  const int lane = tid & 63, w = tid >> 6;
  const int wm = w >> 1, wn = w & 1;
  const int q = lane >> 4, c15 = lane & 15;
  const long row0 = (long)blockIdx.x * 128;
  const long col0 = (long)blockIdx.y * 128;
  floatx4 acc[4][4] = {};

  const int c0 = tid,        r0c = c0 >> 2, p0 = c0 & 3, g0 = p0 ^ ((r0c >> 1) & 3);
  const int c1 = 256 + tid,  r1c = c1 >> 2, p1 = c1 & 3, g1 = p1 ^ ((r1c >> 1) & 3);
  const f16* Arow0 = A  + (row0 + r0c)*384 + g0*8;
  const f16* Arow1 = A  + (row0 + r1c)*384 + g1*8;
  const f16* Brow0 = Bt + (col0 + r0c)*384 + g0*8;
  const f16* Brow1 = Bt + (col0 + r1c)*384 + g1*8;
  const int dof0 = (w*64)*8, dof1 = (256 + w*64)*8;

  for (int k0 = 0; k0 < 384; k0 += 64) {
#pragma unroll
    for (int hf = 0; hf < 2; hf++) {
      int kk = k0 + hf*32;
      g2lds16(Arow0 + kk, &As[hf][dof0]);
      g2lds16(Arow1 + kk, &As[hf][dof1]);
      g2lds16(Brow0 + kk, &Bs[hf][dof0]);
      g2lds16(Brow1 + kk, &Bs[hf][dof1]);
    }
    __syncthreads();
#pragma unroll
    for (int hf = 0; hf < 2; hf++) {
      half8 af[4], bf[4];
#pragma unroll
      for (int mi = 0; mi < 4; mi++) {
        int r = wm*64 + mi*16 + c15;
        int ph = q ^ ((r >> 1) & 3);
        af[mi] = *(const half8*)(&As[hf][r*32 + ph*8]);
      }
#pragma unroll
      for (int ni = 0; ni < 4; ni++) {
        int r = wn*64 + ni*16 + c15;
        int ph = q ^ ((r >> 1) & 3);
        bf[ni] = *(const half8*)(&Bs[hf][r*32 + ph*8]);
      }
#pragma unroll
      for (int mi = 0; mi < 4; mi++)
#pragma unroll
        for (int ni = 0; ni < 4; ni++)
          acc[mi][ni] = __builtin_amdgcn_mfma_f32_16x16x32_f16(af[mi], bf[ni], acc[mi][ni], 0, 0, 0);
    }
    __syncthreads();
  }

#pragma unroll
  for (int ni = 0; ni < 4; ni++) {
    long col = col0 + wn*64 + ni*16 + c15;
    float bv = bias[col];
#pragma unroll
    for (int mi = 0; mi < 4; mi++) {
      long rowb = row0 + wm*64 + mi*16 + q*4;
#pragma unroll
      for (int r = 0; r < 4; r++) {
        outp[(rowb + r) * (long)ldo + col] = (f16)(acc[mi][ni][r] + bv);
      }
    }
  }
}

// ---------------- fused proj + residual + LN2 ----------------
// block = 64 rows x ALL 384 cols; wave owns 16 complete rows -> LN in epilogue.
// outputs: x2 (f32) and h2 (f16).
__global__ __launch_bounds__(256, 1) void projln_kernel(
    const f16* __restrict__ A, const f16* __restrict__ Bt, const float* __restrict__ bias,
    const float* __restrict__ res, const float* __restrict__ g2v, const float* __restrict__ be2,
    float* __restrict__ x2, f16* __restrict__ h2)
{
  __shared__ __align__(16) f16 As2[2][64*32];
  __shared__ __align__(16) f16 Bs2[2][384*32];
  const int tid = threadIdx.x;
  const int lane = tid & 63, w = tid >> 6;
  const int q = lane >> 4, c15 = lane & 15;
  const long row0 = (long)blockIdx.x * 64;
  floatx4 acc[24] = {};

  const int rcA = tid >> 2, pA = tid & 3, gA = pA ^ ((rcA >> 1) & 3);
  const f16* Asrc = A + (row0 + rcA)*384 + gA*8;

  for (int k0 = 0; k0 < 384; k0 += 64) {
#pragma unroll
    for (int hf = 0; hf < 2; hf++) {
      int kk = k0 + hf*32;
      g2lds16(Asrc + kk, &As2[hf][(w*64)*8]);
#pragma unroll
      for (int i = 0; i < 6; i++) {
        int pc = i*256 + tid;
        int rcB = pc >> 2, pB = pc & 3, gB = pB ^ ((rcB >> 1) & 3);
        g2lds16(Bt + (size_t)rcB*384 + kk + gB*8, &Bs2[hf][(i*256 + w*64)*8]);
      }
    }
    __syncthreads();
#pragma unroll
    for (int hf = 0; hf < 2; hf++) {
      int ra = w*16 + c15;
      int pha = q ^ ((ra >> 1) & 3);
      half8 af = *(const half8*)(&As2[hf][ra*32 + pha*8]);
#pragma unroll
      for (int nt = 0; nt < 24; nt++) {
        int rb = nt*16 + c15;
        int phb = q ^ ((rb >> 1) & 3);
        half8 bf = *(const half8*)(&Bs2[hf][rb*32 + phb*8]);
        acc[nt] = __builtin_amdgcn_mfma_f32_16x16x32_f16(af, bf, acc[nt], 0, 0, 0);
      }
    }
    __syncthreads();
  }

  // epilogue: bias + residual (in place), write x2, LN -> h2
  const long rowg = row0 + w*16 + q*4;
#pragma unroll
  for (int nt = 0; nt < 24; nt++) {
    int col = nt*16 + c15;
    float bv = bias[col];
#pragma unroll
    for (int r = 0; r < 4; r++) {
      float v = acc[nt][r] + bv + res[(rowg + r)*384 + col];
      acc[nt][r] = v;
      x2[(rowg + r)*384 + col] = v;
    }
  }
  float s[4] = {0.f, 0.f, 0.f, 0.f};
#pragma unroll
  for (int nt = 0; nt < 24; nt++)
#pragma unroll
    for (int r = 0; r < 4; r++) s[r] += acc[nt][r];
#pragma unroll
  for (int r = 0; r < 4; r++) {
    s[r] += __shfl_xor(s[r], 1);
    s[r] += __shfl_xor(s[r], 2);
    s[r] += __shfl_xor(s[r], 4);
    s[r] += __shfl_xor(s[r], 8);
  }
  float mu[4], vs[4] = {0.f, 0.f, 0.f, 0.f};
#pragma unroll
  for (int r = 0; r < 4; r++) mu[r] = s[r] * (1.f/384.f);
#pragma unroll
  for (int nt = 0; nt < 24; nt++)
#pragma unroll
    for (int r = 0; r < 4; r++) { float d = acc[nt][r] - mu[r]; vs[r] += d*d; }
#pragma unroll
  for (int r = 0; r < 4; r++) {
    vs[r] += __shfl_xor(vs[r], 1);
    vs[r] += __shfl_xor(vs[r], 2);
    vs[r] += __shfl_xor(vs[r], 4);
    vs[r] += __shfl_xor(vs[r], 8);
  }
  float rs[4];
#pragma unroll
  for (int r = 0; r < 4; r++) rs[r] = rsqrtf(vs[r] * (1.f/384.f) + 1e-5f);
#pragma unroll
  for (int nt = 0; nt < 24; nt++) {
    int col = nt*16 + c15;
    float gg = g2v[col], bb = be2[col];
#pragma unroll
    for (int r = 0; r < 4; r++) {
      h2[(rowg + r)*384 + col] = (f16)((acc[nt][r] - mu[r])*rs[r]*gg + bb);
    }
  }
}

// ---------------- fused FFN: out = x2 + relu(h2 @ W1 + b1) @ W2 + b2 ----------------
// block = 64 rows x 384 cols; mid round-trips through LDS (C-layout -> A-layout swizzle).
__global__ __launch_bounds__(256, 1) void ffn_kernel(
    const f16* __restrict__ h2, const f16* __restrict__ W1t, const float* __restrict__ b1,
    const f16* __restrict__ W2t, const float* __restrict__ b2,
    const float* __restrict__ x2, float* __restrict__ outp)
{
  __shared__ __align__(16) f16 As2[2][64*32];
  __shared__ __align__(16) f16 Bs2[2][384*32];
  __shared__ __align__(16) f16 midb[64*384];
  const int tid = threadIdx.x;
  const int lane = tid & 63, w = tid >> 6;
  const int q = lane >> 4, c15 = lane & 15;
  const long row0 = (long)blockIdx.x * 64;

  const int rcA = tid >> 2, pA = tid & 3, gA = pA ^ ((rcA >> 1) & 3);
  const f16* Asrc = h2 + (row0 + rcA)*384 + gA*8;

  // ---- phase 1: mid = relu(h2 @ W1 + b1) -> LDS
  {
    floatx4 acc[24] = {};
    for (int k0 = 0; k0 < 384; k0 += 64) {
#pragma unroll
      for (int hf = 0; hf < 2; hf++) {
        int kk = k0 + hf*32;
        g2lds16(Asrc + kk, &As2[hf][(w*64)*8]);
#pragma unroll
        for (int i = 0; i < 6; i++) {
          int pc = i*256 + tid;
          int rcB = pc >> 2, pB = pc & 3, gB = pB ^ ((rcB >> 1) & 3);
          g2lds16(W1t + (size_t)rcB*384 + kk + gB*8, &Bs2[hf][(i*256 + w*64)*8]);
        }
      }
      __syncthreads();
#pragma unroll
      for (int hf = 0; hf < 2; hf++) {
        int ra = w*16 + c15;
        int pha = q ^ ((ra >> 1) & 3);
        half8 af = *(const half8*)(&As2[hf][ra*32 + pha*8]);
#pragma unroll
        for (int nt = 0; nt < 24; nt++) {
          int rb = nt*16 + c15;
          int phb = q ^ ((rb >> 1) & 3);
          half8 bf = *(const half8*)(&Bs2[hf][rb*32 + phb*8]);
          acc[nt] = __builtin_amdgcn_mfma_f32_16x16x32_f16(af, bf, acc[nt], 0, 0, 0);
        }
      }
      __syncthreads();
    }
    // relu + write mid to LDS (swizzled: phys chunk = chunk ^ (row&7))
#pragma unroll
    for (int nt = 0; nt < 24; nt++) {
      int col = nt*16 + c15;
      float bv = b1[col];
#pragma unroll
      for (int r = 0; r < 4; r++) {
        float v = acc[nt][r] + bv;
        v = v > 0.f ? v : 0.f;
        int row = w*16 + q*4 + r;
        int chunk = col >> 3;
        int ph = chunk ^ (row & 7);
        midb[row*384 + ph*8 + (col & 7)] = (f16)v;
      }
    }
  }
  __syncthreads();

  // ---- phase 2: out = x2 + mid @ W2 + b2
  floatx4 acc2[24] = {};
  for (int k0 = 0; k0 < 384; k0 += 64) {
#pragma unroll
    for (int hf = 0; hf < 2; hf++) {
      int kk = k0 + hf*32;
#pragma unroll
      for (int i = 0; i < 6; i++) {
        int pc = i*256 + tid;
        int rcB = pc >> 2, pB = pc & 3, gB = pB ^ ((rcB >> 1) & 3);
        g2lds16(W2t + (size_t)rcB*384 + kk + gB*8, &Bs2[hf][(i*256 + w*64)*8]);
      }
    }
    __syncthreads();
#pragma unroll
    for (int hf = 0; hf < 2; hf++) {
      int row = w*16 + c15;
      int chunk = (k0 >> 3) + hf*4 + q;
      int ph = chunk ^ (row & 7);
      half8 af = *(const half8*)(&midb[row*384 + ph*8]);
#pragma unroll
      for (int nt = 0; nt < 24; nt++) {
        int rb = nt*16 + c15;
        int phb = q ^ ((rb >> 1) & 3);
        half8 bf = *(const half8*)(&Bs2[hf][rb*32 + phb*8]);
        acc2[nt] = __builtin_amdgcn_mfma_f32_16x16x32_f16(af, bf, acc2[nt], 0, 0, 0);
      }
    }
    __syncthreads();
  }
  const long rowg = row0 + w*16 + q*4;
#pragma unroll
  for (int nt = 0; nt < 24; nt++) {
    int col = nt*16 + c15;
    float bv = b2[col];
#pragma unroll
    for (int r = 0; r < 4; r++) {
      long o = (rowg + r)*384 + col;
      outp[o] = acc2[nt][r] + bv + x2[o];
    }
  }
}

// ---------------- fused causal attention (unchanged) ----------------
__global__ __launch_bounds__(256, 3) void attn_kernel(const f16* __restrict__ qkv,
                                                      f16* __restrict__ attn_out)
{
  __shared__ __align__(16) char kvbuf[32768];
  __shared__ __align__(16) f16 Pbuf[4][16*128];
  f16* Ks = (f16*)kvbuf;
  unsigned int* vTw = (unsigned int*)kvbuf;
  f16* vT = (f16*)kvbuf;

  const int tid = threadIdx.x;
  const int bid = blockIdx.x;
  const int bh = bid >> 2, qt = bid & 3;
  const int b = bh / 6, h = bh - b*6;
  const f16* qp = qkv + (size_t)b*256*1152 + h*64;
  const f16* kp = qp + 384;
  const f16* vp = qp + 768;
  const int lane = tid & 63, w = tid >> 6;
  const int q = lane >> 4, c15 = lane & 15;

  {
    const int iters = (qt + 1) * 2;
    const int pcbase = w*64 + lane;
    for (int i = 0; i < iters; i++) {
      int pc = i*256 + pcbase;
      int rc = pc >> 3, p = pc & 7;
      int c = p ^ (rc & 7);
      g2lds16(kp + (size_t)rc*1152 + c*8, (char*)kvbuf + (size_t)(i*256 + w*64)*16);
    }
  }
  __syncthreads();

  const int nmax = qt*4 + w;
  const int trow0 = qt*64 + w*16;
  const f16* qrow = qp + (size_t)(trow0 + c15)*1152 + q*8;
  half8 aq0 = *(const half8*)(qrow);
  half8 aq1 = *(const half8*)(qrow + 32);

  floatx4 sacc[16];
#pragma unroll
  for (int ni = 0; ni < 16; ni++) {
    if (ni <= nmax) {
      int s = ni*16 + c15;
      const f16* kr = Ks + s*64;
      int p0 = q ^ (s & 7);
      half8 b0 = *(const half8*)(kr + p0*8);
      half8 b1 = *(const half8*)(kr + (p0 ^ 4)*8);
      floatx4 a = {0.f, 0.f, 0.f, 0.f};
      a = __builtin_amdgcn_mfma_f32_16x16x32_f16(aq0, b0, a, 0, 0, 0);
      a = __builtin_amdgcn_mfma_f32_16x16x32_f16(aq1, b1, a, 0, 0, 0);
      sacc[ni] = a;
    }
  }

  const float scale = 0.051031036307982884f;
  float mx[4] = {-1e30f, -1e30f, -1e30f, -1e30f};
#pragma unroll
  for (int ni = 0; ni < 16; ni++) {
    if (ni < nmax) {
#pragma unroll
      for (int r = 0; r < 4; r++) { float v = sacc[ni][r]*scale; sacc[ni][r] = v; mx[r] = fmaxf(mx[r], v); }
    } else if (ni == nmax) {
#pragma unroll
      for (int r = 0; r < 4; r++) {
        float v = sacc[ni][r]*scale;
        v = (c15 <= q*4 + r) ? v : -1e30f;
        sacc[ni][r] = v; mx[r] = fmaxf(mx[r], v);
      }
    }
  }
#pragma unroll
  for (int r = 0; r < 4; r++) {
    mx[r] = fmaxf(mx[r], __shfl_xor(mx[r], 1));
    mx[r] = fmaxf(mx[r], __shfl_xor(mx[r], 2));
    mx[r] = fmaxf(mx[r], __shfl_xor(mx[r], 4));
    mx[r] = fmaxf(mx[r], __shfl_xor(mx[r], 8));
  }
  float l[4] = {0.f, 0.f, 0.f, 0.f};
#pragma unroll
  for (int ni = 0; ni < 16; ni++) {
    if (ni <= nmax) {
#pragma unroll
      for (int r = 0; r < 4; r++) { float p = __expf(sacc[ni][r] - mx[r]); sacc[ni][r] = p; l[r] += p; }
    }
  }
#pragma unroll
  for (int r = 0; r < 4; r++) {
    l[r] += __shfl_xor(l[r], 1);
    l[r] += __shfl_xor(l[r], 2);
    l[r] += __shfl_xor(l[r], 4);
    l[r] += __shfl_xor(l[r], 8);
  }
  __syncthreads();

  {
    const int iters = qt + 1;
    for (int i = 0; i < iters; i++) {
      int idx = i*256 + tid;
      int sp = idx >> 3, part = idx & 7;
      const f16* v0 = vp + (size_t)(2*sp)*1152 + part*8;
      half8 va = *(const half8*)(v0);
      half8 vb = *(const half8*)(v0 + 1152);
      int csp = sp >> 2, spw = sp & 3;
#pragma unroll
      for (int j = 0; j < 8; j++) {
        int d = part*8 + j;
        int swz = (d & 15) ^ (d >> 3);
        int p = csp ^ swz;
        union { struct { f16 lo, hi; } s; unsigned int u; } pk;
        pk.s.lo = va[j]; pk.s.hi = vb[j];
        vTw[d*128 + p*4 + spw] = pk.u;
      }
    }
  }
  __syncthreads();

  f16* Pw = &Pbuf[w][0];
  floatx4 oacc[4] = {};
  const int kend_w = (nmax + 1) * 16;
#pragma unroll
  for (int ch = 0; ch < 2; ch++) {
    if (ch*128 < kend_w) {
#pragma unroll
      for (int nl = 0; nl < 8; nl++) {
        int ni = ch*8 + nl;
        if (ni <= nmax) {
#pragma unroll
          for (int r = 0; r < 4; r++) {
            int row = q*4 + r;
            int colp = nl*16 + c15;
            int php = (colp >> 3) ^ row;
            Pw[row*128 + php*8 + (colp & 7)] = (f16)sacc[ni][r];
          }
        } else if (ni == nmax + 1) {
#pragma unroll
          for (int r = 0; r < 4; r++) {
            int row = q*4 + r;
            int colp = nl*16 + c15;
            int php = (colp >> 3) ^ row;
            Pw[row*128 + php*8 + (colp & 7)] = (f16)0.f;
          }
        }
      }
#pragma unroll
      for (int kc = 0; kc < 4; kc++) {
        if (ch*128 + kc*32 < kend_w) {
          int pc = (kc*4 + q) ^ c15;
          half8 ap = *(const half8*)(Pw + c15*128 + pc*8);
          int sc = ch*16 + kc*4 + q;
#pragma unroll
          for (int nt = 0; nt < 4; nt++) {
            int d = nt*16 + c15;
            int swz = (d & 15) ^ (d >> 3);
            half8 bv = *(const half8*)(vT + d*256 + ((sc ^ swz))*8);
            oacc[nt] = __builtin_amdgcn_mfma_f32_16x16x32_f16(ap, bv, oacc[nt], 0, 0, 0);
          }
        }
      }
    }
  }

#pragma unroll
  for (int nt = 0; nt < 4; nt++) {
#pragma unroll
    for (int r = 0; r < 4; r++) {
      int t = trow0 + q*4 + r;
      int d = nt*16 + c15;
      attn_out[(size_t)(b*256 + t)*384 + h*64 + d] = (f16)(oacc[nt][r] / l[r]);
    }
  }
}

extern "C" void kernel_launch(void* const* d_in, const int* in_sizes, int n_in,
                              void* d_out, int out_size, void* d_ws, size_t ws_size,
                              hipStream_t stream) {
  const float* x   = (const float*)d_in[0];
  const float* Wq  = (const float*)d_in[1];
  const float* bq  = (const float*)d_in[2];
  const float* Wk  = (const float*)d_in[3];
  const float* bk  = (const float*)d_in[4];
  const float* Wv  = (const float*)d_in[5];
  const float* bv  = (const float*)d_in[6];
  const float* Wp  = (const float*)d_in[7];
  const float* bp  = (const float*)d_in[8];
  const float* W1  = (const float*)d_in[9];
  const float* b1  = (const float*)d_in[10];
  const float* W2  = (const float*)d_in[11];
  const float* b2  = (const float*)d_in[12];
  const float* g1  = (const float*)d_in[13];
  const float* be1 = (const float*)d_in[14];
  const float* g2  = (const float*)d_in[15];
  const float* be2 = (const float*)d_in[16];

  char* ws = (char*)d_ws;
  size_t off = 0;
  auto alloc = [&](size_t bytes) -> void* {
    void* p = ws + off;
    off += (bytes + 255) & ~(size_t)255;
    return p;
  };
  f16*   Wqkv_t = (f16*)  alloc(1152*384*sizeof(f16));
  f16*   Wp_t   = (f16*)  alloc(384*384*sizeof(f16));
  f16*   W1_t   = (f16*)  alloc(384*384*sizeof(f16));
  f16*   W2_t   = (f16*)  alloc(384*384*sizeof(f16));
  float* bqkv   = (float*)alloc(1152*sizeof(float));
  f16*   h      = (f16*)  alloc((size_t)NROWS*384*sizeof(f16));
  f16*   qkv    = (f16*)  alloc((size_t)NROWS*1152*sizeof(f16));
  f16*   attnb  = (f16*)  alloc((size_t)NROWS*384*sizeof(f16));
  float* x2     = (float*)alloc((size_t)NROWS*384*sizeof(float));
  f16*   h2     = (f16*)  alloc((size_t)NROWS*384*sizeof(f16));

  // 1. fused: weight repack + LN1
  prep_ln_kernel<<<217 + NROWS/4, 256, 0, stream>>>(Wq, Wk, Wv, bq, bk, bv, Wp, W1, W2,
                                                    Wqkv_t, Wp_t, W1_t, W2_t, bqkv,
                                                    x, g1, be1, h);
  // 2. QKV GEMM
  gemm_qkv_kernel<<<dim3(128, 9), 256, 0, stream>>>(h, Wqkv_t, bqkv, qkv, 1152);
  // 3. attention
  attn_kernel<<<B_*H_*4, 256, 0, stream>>>(qkv, attnb);
  // 4. fused proj + residual + LN2 -> x2 (f32), h2 (f16)
  projln_kernel<<<NROWS/64, 256, 0, stream>>>(attnb, Wp_t, bp, x, g2, be2, x2, h2);
  // 5. fused FFN + residual -> out
  ffn_kernel<<<NROWS/64, 256, 0, stream>>>(h2, W1_t, b1, W2_t, b2, x2, (float*)d_out);
}

// Round 5
// 208.153 us; speedup vs baseline: 1.0594x; 1.0594x over previous
//
#include <hip/hip_runtime.h>

typedef _Float16 f16;
typedef _Float16 half8 __attribute__((ext_vector_type(8)));
typedef _Float16 half4v __attribute__((ext_vector_type(4)));
typedef float floatx4 __attribute__((ext_vector_type(4)));

#define B_ 64
#define T_ 256
#define C_ 384
#define H_ 6
#define D_ 64
#define NROWS (B_*T_)

typedef __attribute__((address_space(3))) void lds_void_t;
typedef const __attribute__((address_space(1))) void gvoid_t;

__device__ __forceinline__ void g2lds16(const void* g, void* l) {
  __builtin_amdgcn_global_load_lds((gvoid_t*)g, (lds_void_t*)l, 16, 0, 0);
}

// ---------------- fused prep (weight repack fp32->f16 B^T) + LN1 ----------------
__global__ __launch_bounds__(256) void prep_ln_kernel(
    const float* __restrict__ Wq, const float* __restrict__ Wk, const float* __restrict__ Wv,
    const float* __restrict__ bq, const float* __restrict__ bk, const float* __restrict__ bv,
    const float* __restrict__ Wp, const float* __restrict__ W1, const float* __restrict__ W2,
    f16* __restrict__ Wqkv_t, f16* __restrict__ Wp_t, f16* __restrict__ W1_t, f16* __restrict__ W2_t,
    float* __restrict__ bqkv,
    const float* __restrict__ x, const float* __restrict__ gamma, const float* __restrict__ beta,
    f16* __restrict__ hout)
{
  const int bid = blockIdx.x;
  const int tid = threadIdx.x;
  if (bid >= 217) {
    int row = (bid - 217) * 4 + (tid >> 6);
    int lane = tid & 63;
    const float* xr = x + (size_t)row * 384;
    float v[6]; float s = 0.f;
#pragma unroll
    for (int j = 0; j < 6; j++) { v[j] = xr[lane + 64*j]; s += v[j]; }
#pragma unroll
    for (int m = 1; m < 64; m <<= 1) s += __shfl_xor(s, m);
    float mu = s * (1.f/384.f);
    float var = 0.f;
#pragma unroll
    for (int j = 0; j < 6; j++) { float d = v[j]-mu; var += d*d; }
#pragma unroll
    for (int m = 1; m < 64; m <<= 1) var += __shfl_xor(var, m);
    float rs = rsqrtf(var * (1.f/384.f) + 1e-5f);
    f16* orow = hout + (size_t)row*384;
#pragma unroll
    for (int j = 0; j < 6; j++) {
      int col = lane + 64*j;
      orow[col] = (f16)((v[j]-mu)*rs*gamma[col] + beta[col]);
    }
    return;
  }
  if (bid == 216) {
    for (int i = tid; i < 1152; i += 256) {
      float v;
      if (i < 384)      v = bq[i];
      else if (i < 768) v = bk[i - 384];
      else              v = bv[i - 768];
      bqkv[i] = v;
    }
    return;
  }
  __shared__ __align__(16) float tile[64*68];
  const float* src; int srcStride; f16* dst;
  if (bid < 108) {
    int mat = bid / 36, rem = bid - mat*36;
    int h = rem / 6, kt = rem - h*6;
    const float* W = (mat == 0) ? Wq : (mat == 1) ? Wk : Wv;
    src = W + (size_t)(h*384 + kt*64)*64;
    srcStride = 64;
    dst = Wqkv_t + (size_t)(mat*384 + h*64)*384 + kt*64;
  } else {
    int b2 = bid - 108;
    int mat = b2 / 36, rem = b2 - mat*36;
    int kt = rem / 6, ct = rem - kt*6;
    const float* W = (mat == 0) ? Wp : (mat == 1) ? W1 : W2;
    src = W + (size_t)(kt*64)*384 + ct*64;
    srcStride = 384;
    f16* O = (mat == 0) ? Wp_t : (mat == 1) ? W1_t : W2_t;
    dst = O + (size_t)(ct*64)*384 + kt*64;
  }
#pragma unroll
  for (int i = 0; i < 4; i++) {
    int idx = i*256 + tid;
    int r = idx >> 4, c4 = idx & 15;
    float4 v = *(const float4*)(src + (size_t)r*srcStride + c4*4);
    *(float4*)(&tile[r*68 + c4*4]) = v;
  }
  __syncthreads();
#pragma unroll
  for (int i = 0; i < 4; i++) {
    int idx = i*256 + tid;
    int d = idx >> 4, k4 = idx & 15;
    half4v o;
#pragma unroll
    for (int j = 0; j < 4; j++) o[j] = (f16)tile[(k4*4 + j)*68 + d];
    *(half4v*)(dst + (size_t)d*384 + k4*4) = o;
  }
}

// ---------------- GEMM (QKV): C[M,1152] = A[M,384] @ Bt^T + bias, 128x128 tile, f16 out ----------
__global__ __launch_bounds__(256) void gemm_qkv_kernel(
    const f16* __restrict__ A, const f16* __restrict__ Bt,
    const float* __restrict__ bias, f16* __restrict__ outp, int ldo)
{
  __shared__ __align__(16) f16 As[2][128*32];
  __shared__ __align__(16) f16 Bs[2][128*32];
  const int tid = threadIdx.x;
  const int lane = tid & 63, w = tid >> 6;
  const int wm = w >> 1, wn = w & 1;
  const int q = lane >> 4, c15 = lane & 15;
  const long row0 = (long)blockIdx.x * 128;
  const long col0 = (long)blockIdx.y * 128;
  floatx4 acc[4][4] = {};

  const int c0 = tid,        r0c = c0 >> 2, p0 = c0 & 3, g0 = p0 ^ ((r0c >> 1) & 3);
  const int c1 = 256 + tid,  r1c = c1 >> 2, p1 = c1 & 3, g1 = p1 ^ ((r1c >> 1) & 3);
  const f16* Arow0 = A  + (row0 + r0c)*384 + g0*8;
  const f16* Arow1 = A  + (row0 + r1c)*384 + g1*8;
  const f16* Brow0 = Bt + (col0 + r0c)*384 + g0*8;
  const f16* Brow1 = Bt + (col0 + r1c)*384 + g1*8;
  const int dof0 = (w*64)*8, dof1 = (256 + w*64)*8;

  for (int k0 = 0; k0 < 384; k0 += 64) {
#pragma unroll
    for (int hf = 0; hf < 2; hf++) {
      int kk = k0 + hf*32;
      g2lds16(Arow0 + kk, &As[hf][dof0]);
      g2lds16(Arow1 + kk, &As[hf][dof1]);
      g2lds16(Brow0 + kk, &Bs[hf][dof0]);
      g2lds16(Brow1 + kk, &Bs[hf][dof1]);
    }
    __syncthreads();
#pragma unroll
    for (int hf = 0; hf < 2; hf++) {
      half8 af[4], bf[4];
#pragma unroll
      for (int mi = 0; mi < 4; mi++) {
        int r = wm*64 + mi*16 + c15;
        int ph = q ^ ((r >> 1) & 3);
        af[mi] = *(const half8*)(&As[hf][r*32 + ph*8]);
      }
#pragma unroll
      for (int ni = 0; ni < 4; ni++) {
        int r = wn*64 + ni*16 + c15;
        int ph = q ^ ((r >> 1) & 3);
        bf[ni] = *(const half8*)(&Bs[hf][r*32 + ph*8]);
      }
#pragma unroll
      for (int mi = 0; mi < 4; mi++)
#pragma unroll
        for (int ni = 0; ni < 4; ni++)
          acc[mi][ni] = __builtin_amdgcn_mfma_f32_16x16x32_f16(af[mi], bf[ni], acc[mi][ni], 0, 0, 0);
    }
    __syncthreads();
  }

#pragma unroll
  for (int ni = 0; ni < 4; ni++) {
    long col = col0 + wn*64 + ni*16 + c15;
    float bv = bias[col];
#pragma unroll
    for (int mi = 0; mi < 4; mi++) {
      long rowb = row0 + wm*64 + mi*16 + q*4;
#pragma unroll
      for (int r = 0; r < 4; r++) {
        outp[(rowb + r) * (long)ldo + col] = (f16)(acc[mi][ni][r] + bv);
      }
    }
  }
}

// ---------------- GEMM64: C[M,384] = A[M,384] @ Bt^T + bias, 128x64 tile, 3 blocks/CU ----------
// MODE 1: relu, f16 out. MODE 2: f32 out + fp32 residual.
template<int MODE>
__global__ __launch_bounds__(256) void gemm64_kernel(
    const f16* __restrict__ A, const f16* __restrict__ Bt,
    const float* __restrict__ bias, const float* __restrict__ res,
    void* __restrict__ outp)
{
  __shared__ __align__(16) f16 As[2][128*32];
  __shared__ __align__(16) f16 Bs[2][64*32];
  const int tid = threadIdx.x;
  const int lane = tid & 63, w = tid >> 6;
  const int wm = w >> 1, wn = w & 1;
  const int q = lane >> 4, c15 = lane & 15;
  const long row0 = (long)blockIdx.x * 128;
  const long col0 = (long)blockIdx.y * 64;
  floatx4 acc[4][2] = {};

  // A: 512 chunks/hf (2 per thread); B: 256 chunks/hf (1 per thread)
  const int cA0 = tid,       rA0 = cA0 >> 2, pA0 = cA0 & 3, gA0 = pA0 ^ ((rA0 >> 1) & 3);
  const int cA1 = 256 + tid, rA1 = cA1 >> 2, pA1 = cA1 & 3, gA1 = pA1 ^ ((rA1 >> 1) & 3);
  const int rB  = tid >> 2,  pB  = tid & 3,  gB  = pB ^ ((rB >> 1) & 3);
  const f16* Arow0 = A  + (row0 + rA0)*384 + gA0*8;
  const f16* Arow1 = A  + (row0 + rA1)*384 + gA1*8;
  const f16* Brow  = Bt + (col0 + rB)*384 + gB*8;
  const int dofA0 = (w*64)*8, dofA1 = (256 + w*64)*8, dofB = (w*64)*8;

  for (int k0 = 0; k0 < 384; k0 += 64) {
#pragma unroll
    for (int hf = 0; hf < 2; hf++) {
      int kk = k0 + hf*32;
      g2lds16(Arow0 + kk, &As[hf][dofA0]);
      g2lds16(Arow1 + kk, &As[hf][dofA1]);
      g2lds16(Brow + kk, &Bs[hf][dofB]);
    }
    __syncthreads();
#pragma unroll
    for (int hf = 0; hf < 2; hf++) {
      half8 af[4], bf[2];
#pragma unroll
      for (int mi = 0; mi < 4; mi++) {
        int r = wm*64 + mi*16 + c15;
        int ph = q ^ ((r >> 1) & 3);
        af[mi] = *(const half8*)(&As[hf][r*32 + ph*8]);
      }
#pragma unroll
      for (int ni = 0; ni < 2; ni++) {
        int r = wn*32 + ni*16 + c15;
        int ph = q ^ ((r >> 1) & 3);
        bf[ni] = *(const half8*)(&Bs[hf][r*32 + ph*8]);
      }
#pragma unroll
      for (int mi = 0; mi < 4; mi++)
#pragma unroll
        for (int ni = 0; ni < 2; ni++)
          acc[mi][ni] = __builtin_amdgcn_mfma_f32_16x16x32_f16(af[mi], bf[ni], acc[mi][ni], 0, 0, 0);
    }
    __syncthreads();
  }

#pragma unroll
  for (int ni = 0; ni < 2; ni++) {
    long col = col0 + wn*32 + ni*16 + c15;
    float bv = bias[col];
#pragma unroll
    for (int mi = 0; mi < 4; mi++) {
      long rowb = row0 + wm*64 + mi*16 + q*4;
#pragma unroll
      for (int r = 0; r < 4; r++) {
        float vo = acc[mi][ni][r] + bv;
        long o = (rowb + r) * 384 + col;
        if (MODE == 1) {
          vo = vo > 0.f ? vo : 0.f;
          ((f16*)outp)[o] = (f16)vo;
        } else {
          ((float*)outp)[o] = vo + res[o];
        }
      }
    }
  }
}

// ---------------- fused proj + residual + LN2, 32-row blocks (grid 512 = 2/CU) ----------------
// block owns 32 full rows; wave w -> col tiles nt = w*6..w*6+5; cross-wave LN via LDS.
__global__ __launch_bounds__(256, 2) void projln2_kernel(
    const f16* __restrict__ A, const f16* __restrict__ Bt, const float* __restrict__ bias,
    const float* __restrict__ res, const float* __restrict__ g2v, const float* __restrict__ be2,
    float* __restrict__ x2, f16* __restrict__ h2)
{
  __shared__ __align__(16) f16 As2[2][32*32];
  __shared__ __align__(16) f16 Bs2[2][384*32];
  __shared__ float redS[4][32], redS2[4][32];
  const int tid = threadIdx.x;
  const int lane = tid & 63, w = tid >> 6;
  const int q = lane >> 4, c15 = lane & 15;
  const long row0 = (long)blockIdx.x * 32;
  floatx4 acc[2][6] = {};

  // A staging: 128 chunks/hf; waves 0,1 -> hf0, waves 2,3 -> hf1
  const int hfA = w >> 1;
  const int idxA = (w & 1)*64 + lane;
  const int rA = idxA >> 2, pA = idxA & 3, gA = pA ^ ((rA >> 1) & 3);
  const f16* Asrc = A + (row0 + rA)*384 + hfA*32 + gA*8;
  f16* Adst = &As2[hfA][((w & 1)*64)*8];

  for (int k0 = 0; k0 < 384; k0 += 64) {
    g2lds16(Asrc + k0, Adst);
#pragma unroll
    for (int hf = 0; hf < 2; hf++) {
#pragma unroll
      for (int i = 0; i < 6; i++) {
        int pc = i*256 + tid;
        int rc = pc >> 2, p = pc & 3, g = p ^ ((rc >> 1) & 3);
        g2lds16(Bt + (size_t)rc*384 + k0 + hf*32 + g*8, &Bs2[hf][(i*256 + w*64)*8]);
      }
    }
    __syncthreads();
#pragma unroll
    for (int hf = 0; hf < 2; hf++) {
      half8 af[2], bf[6];
#pragma unroll
      for (int mi = 0; mi < 2; mi++) {
        int r = mi*16 + c15;
        int ph = q ^ ((r >> 1) & 3);
        af[mi] = *(const half8*)(&As2[hf][r*32 + ph*8]);
      }
#pragma unroll
      for (int j = 0; j < 6; j++) {
        int rb = (w*6 + j)*16 + c15;
        int ph = q ^ ((rb >> 1) & 3);
        bf[j] = *(const half8*)(&Bs2[hf][rb*32 + ph*8]);
      }
#pragma unroll
      for (int mi = 0; mi < 2; mi++)
#pragma unroll
        for (int j = 0; j < 6; j++)
          acc[mi][j] = __builtin_amdgcn_mfma_f32_16x16x32_f16(af[mi], bf[j], acc[mi][j], 0, 0, 0);
    }
    __syncthreads();
  }

  // epilogue: bias + residual, write x2, accumulate row sums/sumsq
  float s[8] = {}, s2[8] = {};
#pragma unroll
  for (int mi = 0; mi < 2; mi++) {
#pragma unroll
    for (int j = 0; j < 6; j++) {
      int col = (w*6 + j)*16 + c15;
      float bv = bias[col];
#pragma unroll
      for (int r = 0; r < 4; r++) {
        long rowg = row0 + mi*16 + q*4 + r;
        float v = acc[mi][j][r] + bv + res[rowg*384 + col];
        acc[mi][j][r] = v;
        x2[rowg*384 + col] = v;
        s[mi*4 + r] += v;
        s2[mi*4 + r] += v*v;
      }
    }
  }
#pragma unroll
  for (int i = 0; i < 8; i++) {
#pragma unroll
    for (int m = 1; m <= 8; m <<= 1) {
      s[i]  += __shfl_xor(s[i], m);
      s2[i] += __shfl_xor(s2[i], m);
    }
  }
  if (c15 == 0) {
#pragma unroll
    for (int mi = 0; mi < 2; mi++)
#pragma unroll
      for (int r = 0; r < 4; r++) {
        redS[w][mi*16 + q*4 + r]  = s[mi*4 + r];
        redS2[w][mi*16 + q*4 + r] = s2[mi*4 + r];
      }
  }
  __syncthreads();
  float mu[8], rs[8];
#pragma unroll
  for (int mi = 0; mi < 2; mi++)
#pragma unroll
    for (int r = 0; r < 4; r++) {
      int row = mi*16 + q*4 + r;
      float S  = redS[0][row] + redS[1][row] + redS[2][row] + redS[3][row];
      float S2 = redS2[0][row] + redS2[1][row] + redS2[2][row] + redS2[3][row];
      float m_ = S * (1.f/384.f);
      float var = S2 * (1.f/384.f) - m_*m_;
      mu[mi*4 + r] = m_;
      rs[mi*4 + r] = rsqrtf(var + 1e-5f);
    }
#pragma unroll
  for (int mi = 0; mi < 2; mi++) {
#pragma unroll
    for (int j = 0; j < 6; j++) {
      int col = (w*6 + j)*16 + c15;
      float gg = g2v[col], bb = be2[col];
#pragma unroll
      for (int r = 0; r < 4; r++) {
        long rowg = row0 + mi*16 + q*4 + r;
        h2[rowg*384 + col] = (f16)((acc[mi][j][r] - mu[mi*4 + r])*rs[mi*4 + r]*gg + bb);
      }
    }
  }
}

// ---------------- fused causal attention (unchanged) ----------------
__global__ __launch_bounds__(256, 3) void attn_kernel(const f16* __restrict__ qkv,
                                                      f16* __restrict__ attn_out)
{
  __shared__ __align__(16) char kvbuf[32768];
  __shared__ __align__(16) f16 Pbuf[4][16*128];
  f16* Ks = (f16*)kvbuf;
  unsigned int* vTw = (unsigned int*)kvbuf;
  f16* vT = (f16*)kvbuf;

  const int tid = threadIdx.x;
  const int bid = blockIdx.x;
  const int bh = bid >> 2, qt = bid & 3;
  const int b = bh / 6, h = bh - b*6;
  const f16* qp = qkv + (size_t)b*256*1152 + h*64;
  const f16* kp = qp + 384;
  const f16* vp = qp + 768;
  const int lane = tid & 63, w = tid >> 6;
  const int q = lane >> 4, c15 = lane & 15;

  {
    const int iters = (qt + 1) * 2;
    const int pcbase = w*64 + lane;
    for (int i = 0; i < iters; i++) {
      int pc = i*256 + pcbase;
      int rc = pc >> 3, p = pc & 7;
      int c = p ^ (rc & 7);
      g2lds16(kp + (size_t)rc*1152 + c*8, (char*)kvbuf + (size_t)(i*256 + w*64)*16);
    }
  }
  __syncthreads();

  const int nmax = qt*4 + w;
  const int trow0 = qt*64 + w*16;
  const f16* qrow = qp + (size_t)(trow0 + c15)*1152 + q*8;
  half8 aq0 = *(const half8*)(qrow);
  half8 aq1 = *(const half8*)(qrow + 32);

  floatx4 sacc[16];
#pragma unroll
  for (int ni = 0; ni < 16; ni++) {
    if (ni <= nmax) {
      int s = ni*16 + c15;
      const f16* kr = Ks + s*64;
      int p0 = q ^ (s & 7);
      half8 b0 = *(const half8*)(kr + p0*8);
      half8 b1 = *(const half8*)(kr + (p0 ^ 4)*8);
      floatx4 a = {0.f, 0.f, 0.f, 0.f};
      a = __builtin_amdgcn_mfma_f32_16x16x32_f16(aq0, b0, a, 0, 0, 0);
      a = __builtin_amdgcn_mfma_f32_16x16x32_f16(aq1, b1, a, 0, 0, 0);
      sacc[ni] = a;
    }
  }

  const float scale = 0.051031036307982884f;
  float mx[4] = {-1e30f, -1e30f, -1e30f, -1e30f};
#pragma unroll
  for (int ni = 0; ni < 16; ni++) {
    if (ni < nmax) {
#pragma unroll
      for (int r = 0; r < 4; r++) { float v = sacc[ni][r]*scale; sacc[ni][r] = v; mx[r] = fmaxf(mx[r], v); }
    } else if (ni == nmax) {
#pragma unroll
      for (int r = 0; r < 4; r++) {
        float v = sacc[ni][r]*scale;
        v = (c15 <= q*4 + r) ? v : -1e30f;
        sacc[ni][r] = v; mx[r] = fmaxf(mx[r], v);
      }
    }
  }
#pragma unroll
  for (int r = 0; r < 4; r++) {
    mx[r] = fmaxf(mx[r], __shfl_xor(mx[r], 1));
    mx[r] = fmaxf(mx[r], __shfl_xor(mx[r], 2));
    mx[r] = fmaxf(mx[r], __shfl_xor(mx[r], 4));
    mx[r] = fmaxf(mx[r], __shfl_xor(mx[r], 8));
  }
  float l[4] = {0.f, 0.f, 0.f, 0.f};
#pragma unroll
  for (int ni = 0; ni < 16; ni++) {
    if (ni <= nmax) {
#pragma unroll
      for (int r = 0; r < 4; r++) { float p = __expf(sacc[ni][r] - mx[r]); sacc[ni][r] = p; l[r] += p; }
    }
  }
#pragma unroll
  for (int r = 0; r < 4; r++) {
    l[r] += __shfl_xor(l[r], 1);
    l[r] += __shfl_xor(l[r], 2);
    l[r] += __shfl_xor(l[r], 4);
    l[r] += __shfl_xor(l[r], 8);
  }
  __syncthreads();

  {
    const int iters = qt + 1;
    for (int i = 0; i < iters; i++) {
      int idx = i*256 + tid;
      int sp = idx >> 3, part = idx & 7;
      const f16* v0 = vp + (size_t)(2*sp)*1152 + part*8;
      half8 va = *(const half8*)(v0);
      half8 vb = *(const half8*)(v0 + 1152);
      int csp = sp >> 2, spw = sp & 3;
#pragma unroll
      for (int j = 0; j < 8; j++) {
        int d = part*8 + j;
        int swz = (d & 15) ^ (d >> 3);
        int p = csp ^ swz;
        union { struct { f16 lo, hi; } s; unsigned int u; } pk;
        pk.s.lo = va[j]; pk.s.hi = vb[j];
        vTw[d*128 + p*4 + spw] = pk.u;
      }
    }
  }
  __syncthreads();

  f16* Pw = &Pbuf[w][0];
  floatx4 oacc[4] = {};
  const int kend_w = (nmax + 1) * 16;
#pragma unroll
  for (int ch = 0; ch < 2; ch++) {
    if (ch*128 < kend_w) {
#pragma unroll
      for (int nl = 0; nl < 8; nl++) {
        int ni = ch*8 + nl;
        if (ni <= nmax) {
#pragma unroll
          for (int r = 0; r < 4; r++) {
            int row = q*4 + r;
            int colp = nl*16 + c15;
            int php = (colp >> 3) ^ row;
            Pw[row*128 + php*8 + (colp & 7)] = (f16)sacc[ni][r];
          }
        } else if (ni == nmax + 1) {
#pragma unroll
          for (int r = 0; r < 4; r++) {
            int row = q*4 + r;
            int colp = nl*16 + c15;
            int php = (colp >> 3) ^ row;
            Pw[row*128 + php*8 + (colp & 7)] = (f16)0.f;
          }
        }
      }
#pragma unroll
      for (int kc = 0; kc < 4; kc++) {
        if (ch*128 + kc*32 < kend_w) {
          int pc = (kc*4 + q) ^ c15;
          half8 ap = *(const half8*)(Pw + c15*128 + pc*8);
          int sc = ch*16 + kc*4 + q;
#pragma unroll
          for (int nt = 0; nt < 4; nt++) {
            int d = nt*16 + c15;
            int swz = (d & 15) ^ (d >> 3);
            half8 bv = *(const half8*)(vT + d*256 + ((sc ^ swz))*8);
            oacc[nt] = __builtin_amdgcn_mfma_f32_16x16x32_f16(ap, bv, oacc[nt], 0, 0, 0);
          }
        }
      }
    }
  }

#pragma unroll
  for (int nt = 0; nt < 4; nt++) {
#pragma unroll
    for (int r = 0; r < 4; r++) {
      int t = trow0 + q*4 + r;
      int d = nt*16 + c15;
      attn_out[(size_t)(b*256 + t)*384 + h*64 + d] = (f16)(oacc[nt][r] / l[r]);
    }
  }
}

extern "C" void kernel_launch(void* const* d_in, const int* in_sizes, int n_in,
                              void* d_out, int out_size, void* d_ws, size_t ws_size,
                              hipStream_t stream) {
  const float* x   = (const float*)d_in[0];
  const float* Wq  = (const float*)d_in[1];
  const float* bq  = (const float*)d_in[2];
  const float* Wk  = (const float*)d_in[3];
  const float* bk  = (const float*)d_in[4];
  const float* Wv  = (const float*)d_in[5];
  const float* bv  = (const float*)d_in[6];
  const float* Wp  = (const float*)d_in[7];
  const float* bp  = (const float*)d_in[8];
  const float* W1  = (const float*)d_in[9];
  const float* b1  = (const float*)d_in[10];
  const float* W2  = (const float*)d_in[11];
  const float* b2  = (const float*)d_in[12];
  const float* g1  = (const float*)d_in[13];
  const float* be1 = (const float*)d_in[14];
  const float* g2  = (const float*)d_in[15];
  const float* be2 = (const float*)d_in[16];

  char* ws = (char*)d_ws;
  size_t off = 0;
  auto alloc = [&](size_t bytes) -> void* {
    void* p = ws + off;
    off += (bytes + 255) & ~(size_t)255;
    return p;
  };
  f16*   Wqkv_t = (f16*)  alloc(1152*384*sizeof(f16));
  f16*   Wp_t   = (f16*)  alloc(384*384*sizeof(f16));
  f16*   W1_t   = (f16*)  alloc(384*384*sizeof(f16));
  f16*   W2_t   = (f16*)  alloc(384*384*sizeof(f16));
  float* bqkv   = (float*)alloc(1152*sizeof(float));
  f16*   h      = (f16*)  alloc((size_t)NROWS*384*sizeof(f16));
  f16*   qkv    = (f16*)  alloc((size_t)NROWS*1152*sizeof(f16));
  f16*   attnb  = (f16*)  alloc((size_t)NROWS*384*sizeof(f16));
  float* x2     = (float*)alloc((size_t)NROWS*384*sizeof(float));
  f16*   h2     = (f16*)  alloc((size_t)NROWS*384*sizeof(f16));
  f16*   mid    = (f16*)  alloc((size_t)NROWS*384*sizeof(f16));

  // 1. fused: weight repack + LN1
  prep_ln_kernel<<<217 + NROWS/4, 256, 0, stream>>>(Wq, Wk, Wv, bq, bk, bv, Wp, W1, W2,
                                                    Wqkv_t, Wp_t, W1_t, W2_t, bqkv,
                                                    x, g1, be1, h);
  // 2. QKV GEMM
  gemm_qkv_kernel<<<dim3(128, 9), 256, 0, stream>>>(h, Wqkv_t, bqkv, qkv, 1152);
  // 3. attention
  attn_kernel<<<B_*H_*4, 256, 0, stream>>>(qkv, attnb);
  // 4. fused proj + residual + LN2 -> x2 (f32), h2 (f16)   [32-row blocks, 2/CU]
  projln2_kernel<<<NROWS/32, 256, 0, stream>>>(attnb, Wp_t, bp, x, g2, be2, x2, h2);
  // 5. FF1: mid = relu(h2 @ W1 + b1)  [128x64 tiles, 768 blocks]
  gemm64_kernel<1><<<dim3(128, 6), 256, 0, stream>>>(h2, W1_t, b1, nullptr, mid);
  // 6. FF2: out = x2 + mid @ W2 + b2
  gemm64_kernel<2><<<dim3(128, 6), 256, 0, stream>>>(mid, W2_t, b2, x2, (float*)d_out);
}